// Round 3
// baseline (44089.078 us; speedup 1.0000x reference)
//
#include <hip/hip_runtime.h>

// (T,B,I,H) = (1024, 64, 512, 512)
#define T_STEPS 1024
#define BATCH   64
#define IN_F    512
#define HID     512
#define G3      1536
#define M_ROWS  (T_STEPS * BATCH)

#define NSLICE  16   // weight-row slices (96 rows each, reg-resident)
#define NGROUP  16   // batch groups (4 sequences each)
#define SPG     4    // sequences per group

typedef _Float16 v8h  __attribute__((ext_vector_type(8)));
typedef float    v4f  __attribute__((ext_vector_type(4)));

// ---------------------------------------------------------------------------
// gx = x * w_ih^T + b_ih -> f16 [65536][1536]   (unchanged from round 1, passed)
// ---------------------------------------------------------------------------
#define BM 64
#define BN 128
#define BK 32
#define LDP 40

__global__ __launch_bounds__(256) void gemm_gx(
    const float* __restrict__ X, const float* __restrict__ W,
    const float* __restrict__ bias, _Float16* __restrict__ C) {
  __shared__ _Float16 As[BM][LDP];
  __shared__ _Float16 Bs[BN][LDP];
  const int tid  = threadIdx.x;
  const int lane = tid & 63;
  const int wave = tid >> 6;
  const int m0 = blockIdx.y * BM;
  const int n0 = blockIdx.x * BN;

  v4f acc[8];
#pragma unroll
  for (int i = 0; i < 8; ++i) acc[i] = (v4f){0.f, 0.f, 0.f, 0.f};

  const int srow  = tid >> 2;
  const int kpart = (tid & 3) * 8;
  const int fr = lane & 15;
  const int ko = (lane >> 4) * 8;

  for (int kc = 0; kc < IN_F; kc += BK) {
    {
      const float* s = X + (size_t)(m0 + srow) * IN_F + kc + kpart;
      float4 a = *(const float4*)s;
      float4 b = *(const float4*)(s + 4);
      v8h o = {(_Float16)a.x, (_Float16)a.y, (_Float16)a.z, (_Float16)a.w,
               (_Float16)b.x, (_Float16)b.y, (_Float16)b.z, (_Float16)b.w};
      *(v8h*)&As[srow][kpart] = o;
    }
#pragma unroll
    for (int r = 0; r < 2; ++r) {
      const float* s = W + (size_t)(n0 + r * 64 + srow) * IN_F + kc + kpart;
      float4 a = *(const float4*)s;
      float4 b = *(const float4*)(s + 4);
      v8h o = {(_Float16)a.x, (_Float16)a.y, (_Float16)a.z, (_Float16)a.w,
               (_Float16)b.x, (_Float16)b.y, (_Float16)b.z, (_Float16)b.w};
      *(v8h*)&Bs[r * 64 + srow][kpart] = o;
    }
    __syncthreads();
    v8h af = *(const v8h*)&As[wave * 16 + fr][ko];
#pragma unroll
    for (int nt = 0; nt < 8; ++nt) {
      v8h bf = *(const v8h*)&Bs[nt * 16 + fr][ko];
      acc[nt] = __builtin_amdgcn_mfma_f32_16x16x32_f16(af, bf, acc[nt], 0, 0, 0);
    }
    __syncthreads();
  }

  const int rq = lane >> 4;
#pragma unroll
  for (int nt = 0; nt < 8; ++nt) {
    const int gcol = n0 + nt * 16 + fr;
    const float bv = bias[gcol];
#pragma unroll
    for (int r = 0; r < 4; ++r) {
      const int grow = m0 + wave * 16 + rq * 4 + r;
      C[(size_t)grow * G3 + gcol] = (_Float16)(acc[nt][r] + bv);
    }
  }
}

// ---------------------------------------------------------------------------
// Zero the epoch counters without hipMemsetAsync (graph-capture-safe,
// stream-ordered before the scan).
// ---------------------------------------------------------------------------
__global__ void zero_cnt(unsigned int* cnt) { cnt[threadIdx.x] = 0u; }

// ---------------------------------------------------------------------------
// Persistent-weight GRU scan. 256 WGs = 16 slices x 16 groups; WG = 192
// threads (3 waves = 3 gates). Wave w holds gate-w weight slice (32 rows x
// 512 K) as 32 persistent MFMA B-frags (128 VGPR/lane). Per step:
// gh = mfma(h_frag, w_frag), seqs on the M dim; slices exchange their
// 32 h-columns via a global f16 ping-pong buffer + per-group epoch counter.
// Plain launch, NOT cooperative: __launch_bounds__(192,2) caps VGPR at 256
// => >=2 blocks/CU capacity => 256 blocks always co-resident => spin barrier
// cannot deadlock.
// MFMA mapping identical to gemm_gx above (verified passing):
//   A lane: m=lane&15, k=(lane>>4)*8+j ; D: n=lane&15, m=(lane>>4)*4+reg.
// ---------------------------------------------------------------------------
__global__ __launch_bounds__(192, 2) void gru_scan2(
    const _Float16* __restrict__ gx, const float* __restrict__ whh,
    const int* __restrict__ lens, const float* __restrict__ bhh,
    float* __restrict__ out, _Float16* hbuf, unsigned int* cnt) {
  const int bid   = blockIdx.x;
  const int slice = bid >> 4;
  const int grp   = bid & 15;
  const int b0  = grp * SPG;
  const int tid  = threadIdx.x;
  const int lane = tid & 63;
  const int w    = tid >> 6;    // wave = gate (0:r 1:z 2:n)

  __shared__ __align__(16) _Float16 h16[16 * 520];  // +8 pad
  __shared__ __align__(16) float ghl[3 * 32 * 4];   // [gate][col][seq]

  for (int i = tid; i < 16 * 520 / 2; i += 192) ((unsigned*)h16)[i] = 0u;

  // ---- persistent weight B-frags: wave w, rows = w*512 + slice*32 + [0,32)
  v8h bw0[16], bw1[16];
  {
    const int r15 = lane & 15;
    const int k8  = (lane >> 4) * 8;
    const float* p0 = whh + (size_t)(w * 512 + slice * 32 + r15) * HID + k8;
    const float* p1 = p0 + 16 * HID;
#pragma unroll
    for (int kt = 0; kt < 16; ++kt) {
      float4 a = *(const float4*)(p0 + kt * 32);
      float4 b = *(const float4*)(p0 + kt * 32 + 4);
      bw0[kt] = (v8h){(_Float16)a.x, (_Float16)a.y, (_Float16)a.z, (_Float16)a.w,
                      (_Float16)b.x, (_Float16)b.y, (_Float16)b.z, (_Float16)b.w};
      float4 c = *(const float4*)(p1 + kt * 32);
      float4 d = *(const float4*)(p1 + kt * 32 + 4);
      bw1[kt] = (v8h){(_Float16)c.x, (_Float16)c.y, (_Float16)c.z, (_Float16)c.w,
                      (_Float16)d.x, (_Float16)d.y, (_Float16)d.z, (_Float16)d.w};
    }
  }

  // ---- epilogue thread state: tid<64 owns (seq = tid>>4, cols ec0,ec0+1)
  const int eseq = tid >> 4;
  const int ec0  = (tid & 15) * 2;
  const int ej   = slice * 32 + ec0;
  float hr0 = 0.f, hr1 = 0.f;
  float br0 = 0, br1 = 0, bz0 = 0, bz1 = 0, bn0 = 0, bn1 = 0;
  int mylen = 0;
  if (tid < 64) {
    br0 = bhh[ej];        br1 = bhh[ej + 1];
    bz0 = bhh[ej + 512];  bz1 = bhh[ej + 513];
    bn0 = bhh[ej + 1024]; bn1 = bhh[ej + 1025];
    mylen = lens[b0 + eseq];
  }
  const int glen = max(max(lens[b0], lens[b0 + 1]), max(lens[b0 + 2], lens[b0 + 3]));
  unsigned int* cntp = cnt + grp * 32;  // 128B-spaced counters
  __syncthreads();

  const int arow = lane & 15;
  const int ak   = (lane >> 4) * 8;
  const _Float16* hbase = &h16[arow * 520 + ak];

  for (int t = 0; t < glen; ++t) {
    // ---- matvec: gh[seq][row] for this wave's 32 rows
    v4f acc0 = (v4f){0.f, 0.f, 0.f, 0.f};
    v4f acc1 = (v4f){0.f, 0.f, 0.f, 0.f};
#pragma unroll
    for (int kt = 0; kt < 16; ++kt) {
      v8h af = *(const v8h*)(hbase + kt * 32);
      acc0 = __builtin_amdgcn_mfma_f32_16x16x32_f16(af, bw0[kt], acc0, 0, 0, 0);
      acc1 = __builtin_amdgcn_mfma_f32_16x16x32_f16(af, bw1[kt], acc1, 0, 0, 0);
    }
    if (lane < 16) {  // lanes 0..15: reg p = seq p, col n = lane
      *(v4f*)&ghl[(w * 32 + lane) * 4]      = acc0;
      *(v4f*)&ghl[(w * 32 + 16 + lane) * 4] = acc1;
    }
    __syncthreads();

    if (tid < 64) {
      const float ar0 = ghl[(0 * 32 + ec0) * 4 + eseq], ar1 = ghl[(0 * 32 + ec0 + 1) * 4 + eseq];
      const float az0 = ghl[(1 * 32 + ec0) * 4 + eseq], az1 = ghl[(1 * 32 + ec0 + 1) * 4 + eseq];
      const float an0 = ghl[(2 * 32 + ec0) * 4 + eseq], an1 = ghl[(2 * 32 + ec0 + 1) * 4 + eseq];
      const _Float16* gxr = gx + ((size_t)t * BATCH + b0 + eseq) * G3 + ej;
      union { unsigned u; _Float16 h[2]; } g0, g1, g2, pk;
      g0.u = *(const unsigned*)gxr;
      g1.u = *(const unsigned*)(gxr + 512);
      g2.u = *(const unsigned*)(gxr + 1024);
      float* o = out + (size_t)t * (BATCH * HID) + (size_t)(b0 + eseq) * HID + ej;
      if (t < mylen) {
        const float r0 = 1.f / (1.f + __expf(-((float)g0.h[0] + ar0 + br0)));
        const float z0 = 1.f / (1.f + __expf(-((float)g1.h[0] + az0 + bz0)));
        const float p0 = (float)g2.h[0] + r0 * (an0 + bn0);
        const float n0v = 1.f - 2.f / (__expf(2.f * p0) + 1.f);
        hr0 = (1.f - z0) * n0v + z0 * hr0;
        const float r1 = 1.f / (1.f + __expf(-((float)g0.h[1] + ar1 + br1)));
        const float z1 = 1.f / (1.f + __expf(-((float)g1.h[1] + az1 + bz1)));
        const float p1 = (float)g2.h[1] + r1 * (an1 + bn1);
        const float n1v = 1.f - 2.f / (__expf(2.f * p1) + 1.f);
        hr1 = (1.f - z1) * n1v + z1 * hr1;
        o[0] = hr0; o[1] = hr1;
      } else {
        o[0] = 0.f; o[1] = 0.f;  // zero-padded past sequence end
      }
      // publish h (frozen value if inactive) to ping-pong buffer, agent scope
      pk.h[0] = (_Float16)hr0; pk.h[1] = (_Float16)hr1;
      const size_t di = (size_t)((((t + 1) & 1) * NGROUP + grp) * SPG + eseq) * 256
                        + slice * 16 + (tid & 15);
      __hip_atomic_store((unsigned*)hbuf + di, pk.u, __ATOMIC_RELEASE,
                         __HIP_MEMORY_SCOPE_AGENT);
    }
    __threadfence();
    __syncthreads();
    if (tid == 0) {
      __hip_atomic_fetch_add(cntp, 1u, __ATOMIC_RELEASE, __HIP_MEMORY_SCOPE_AGENT);
      const unsigned target = (unsigned)(t + 1) * NSLICE;
      while (__hip_atomic_load(cntp, __ATOMIC_ACQUIRE, __HIP_MEMORY_SCOPE_AGENT) < target)
        __builtin_amdgcn_s_sleep(2);
    }
    __syncthreads();
    __threadfence();
    // ---- pull full h for next step: 4 seq x 512 f16 = 1024 uints
    const unsigned* src = (const unsigned*)hbuf
        + (size_t)(((t + 1) & 1) * NGROUP + grp) * SPG * 256;
    for (int i = tid; i < SPG * 256; i += 192) {
      const unsigned v = __hip_atomic_load(src + i, __ATOMIC_ACQUIRE,
                                           __HIP_MEMORY_SCOPE_AGENT);
      const int sq = i >> 8, i2 = i & 255;
      *(unsigned*)&h16[sq * 520 + i2 * 2] = v;
    }
    __syncthreads();
  }

  if (tid < 64) {
    for (int t = glen; t < T_STEPS; ++t) {
      float* o = out + (size_t)t * (BATCH * HID) + (size_t)(b0 + eseq) * HID + ej;
      o[0] = 0.f; o[1] = 0.f;
    }
    float* hl = out + (size_t)T_STEPS * BATCH * HID + (size_t)(b0 + eseq) * HID + ej;
    hl[0] = hr0; hl[1] = hr1;
  }
}

// ---------------------------------------------------------------------------
extern "C" void kernel_launch(void* const* d_in, const int* in_sizes, int n_in,
                              void* d_out, int out_size, void* d_ws, size_t ws_size,
                              hipStream_t stream) {
  const float* x    = (const float*)d_in[0];
  const int*   lens = (const int*)d_in[1];
  const float* w_ih = (const float*)d_in[2];
  const float* w_hh = (const float*)d_in[3];
  const float* b_ih = (const float*)d_in[4];
  const float* b_hh = (const float*)d_in[5];
  float* out = (float*)d_out;

  // ws: gx f16 [65536][1536] = 192 MiB | hbuf f16 2x16x4x512 = 128 KiB | cnt 2 KiB
  _Float16* gxbuf = (_Float16*)d_ws;
  _Float16* hbuf  = gxbuf + (size_t)M_ROWS * G3;
  unsigned int* cnt = (unsigned int*)(hbuf + 2 * NGROUP * SPG * HID);

  zero_cnt<<<dim3(1), dim3(NGROUP * 32), 0, stream>>>(cnt);
  gemm_gx<<<dim3(G3 / BN, M_ROWS / BM), dim3(256), 0, stream>>>(x, w_ih, b_ih, gxbuf);
  gru_scan2<<<dim3(NSLICE * NGROUP), dim3(192), 0, stream>>>(
      gxbuf, w_hh, lens, b_hh, out, hbuf, cnt);
}

// Round 4
// 4652.386 us; speedup vs baseline: 9.4767x; 9.4767x over previous
//
#include <hip/hip_runtime.h>

// (T,B,I,H) = (1024, 64, 512, 512)
#define T_STEPS 1024
#define BATCH   64
#define IN_F    512
#define HID     512
#define G3      1536
#define M_ROWS  (T_STEPS * BATCH)

#define NSLICE  16   // weight-row slices (96 rows each, reg-resident)
#define NGROUP  16   // batch groups (4 sequences each)
#define SPG     4    // sequences per group

typedef _Float16 v8h  __attribute__((ext_vector_type(8)));
typedef float    v4f  __attribute__((ext_vector_type(4)));

// ---------------------------------------------------------------------------
// gx = x * w_ih^T + b_ih -> f16 [65536][1536]   (unchanged, passing)
// ---------------------------------------------------------------------------
#define BM 64
#define BN 128
#define BK 32
#define LDP 40

__global__ __launch_bounds__(256) void gemm_gx(
    const float* __restrict__ X, const float* __restrict__ W,
    const float* __restrict__ bias, _Float16* __restrict__ C) {
  __shared__ _Float16 As[BM][LDP];
  __shared__ _Float16 Bs[BN][LDP];
  const int tid  = threadIdx.x;
  const int lane = tid & 63;
  const int wave = tid >> 6;
  const int m0 = blockIdx.y * BM;
  const int n0 = blockIdx.x * BN;

  v4f acc[8];
#pragma unroll
  for (int i = 0; i < 8; ++i) acc[i] = (v4f){0.f, 0.f, 0.f, 0.f};

  const int srow  = tid >> 2;
  const int kpart = (tid & 3) * 8;
  const int fr = lane & 15;
  const int ko = (lane >> 4) * 8;

  for (int kc = 0; kc < IN_F; kc += BK) {
    {
      const float* s = X + (size_t)(m0 + srow) * IN_F + kc + kpart;
      float4 a = *(const float4*)s;
      float4 b = *(const float4*)(s + 4);
      v8h o = {(_Float16)a.x, (_Float16)a.y, (_Float16)a.z, (_Float16)a.w,
               (_Float16)b.x, (_Float16)b.y, (_Float16)b.z, (_Float16)b.w};
      *(v8h*)&As[srow][kpart] = o;
    }
#pragma unroll
    for (int r = 0; r < 2; ++r) {
      const float* s = W + (size_t)(n0 + r * 64 + srow) * IN_F + kc + kpart;
      float4 a = *(const float4*)s;
      float4 b = *(const float4*)(s + 4);
      v8h o = {(_Float16)a.x, (_Float16)a.y, (_Float16)a.z, (_Float16)a.w,
               (_Float16)b.x, (_Float16)b.y, (_Float16)b.z, (_Float16)b.w};
      *(v8h*)&Bs[r * 64 + srow][kpart] = o;
    }
    __syncthreads();
    v8h af = *(const v8h*)&As[wave * 16 + fr][ko];
#pragma unroll
    for (int nt = 0; nt < 8; ++nt) {
      v8h bf = *(const v8h*)&Bs[nt * 16 + fr][ko];
      acc[nt] = __builtin_amdgcn_mfma_f32_16x16x32_f16(af, bf, acc[nt], 0, 0, 0);
    }
    __syncthreads();
  }

  const int rq = lane >> 4;
#pragma unroll
  for (int nt = 0; nt < 8; ++nt) {
    const int gcol = n0 + nt * 16 + fr;
    const float bv = bias[gcol];
#pragma unroll
    for (int r = 0; r < 4; ++r) {
      const int grow = m0 + wave * 16 + rq * 4 + r;
      C[(size_t)grow * G3 + gcol] = (_Float16)(acc[nt][r] + bv);
    }
  }
}

__global__ void zero_flags(unsigned int* f) { f[threadIdx.x] = 0u; }

// ---------------------------------------------------------------------------
// Persistent-weight GRU scan. Topology/datapath identical to round 3 (passed,
// absmax 0.0039). Sync rebuilt cache-op-free:
//  - h publish/pull + flags: RELAXED agent-scope atomics -> sc1 (bypass the
//    non-coherent XCD L2, no buffer_inv/buffer_wbl2 in the hot loop).
//  - per-(grp,slice) monotone flags, one 64B line per group; 16 lanes poll.
//  - publish completeness before flag: __syncthreads() vmcnt(0) drain.
// Plain launch; __launch_bounds__(192,2) => 256 blocks always co-resident.
// ---------------------------------------------------------------------------
__global__ __launch_bounds__(192, 2) void gru_scan2(
    const _Float16* __restrict__ gx, const float* __restrict__ whh,
    const int* __restrict__ lens, const float* __restrict__ bhh,
    float* __restrict__ out, _Float16* hbuf, unsigned int* flags) {
  const int bid   = blockIdx.x;
  const int slice = bid >> 4;
  const int grp   = bid & 15;   // slices of a group land co-XCD under %8 rr
  const int b0  = grp * SPG;
  const int tid  = threadIdx.x;
  const int lane = tid & 63;
  const int w    = tid >> 6;    // wave = gate (0:r 1:z 2:n)

  __shared__ __align__(16) _Float16 h16[16 * 520];  // +8 pad
  __shared__ __align__(16) float ghl[3 * 32 * 4];   // [gate][col][seq]

  for (int i = tid; i < 16 * 520 / 2; i += 192) ((unsigned*)h16)[i] = 0u;

  // ---- persistent weight B-frags: wave w, rows = w*512 + slice*32 + [0,32)
  v8h bw0[16], bw1[16];
  {
    const int r15 = lane & 15;
    const int k8  = (lane >> 4) * 8;
    const float* p0 = whh + (size_t)(w * 512 + slice * 32 + r15) * HID + k8;
    const float* p1 = p0 + 16 * HID;
#pragma unroll
    for (int kt = 0; kt < 16; ++kt) {
      float4 a = *(const float4*)(p0 + kt * 32);
      float4 b = *(const float4*)(p0 + kt * 32 + 4);
      bw0[kt] = (v8h){(_Float16)a.x, (_Float16)a.y, (_Float16)a.z, (_Float16)a.w,
                      (_Float16)b.x, (_Float16)b.y, (_Float16)b.z, (_Float16)b.w};
      float4 c = *(const float4*)(p1 + kt * 32);
      float4 d = *(const float4*)(p1 + kt * 32 + 4);
      bw1[kt] = (v8h){(_Float16)c.x, (_Float16)c.y, (_Float16)c.z, (_Float16)c.w,
                      (_Float16)d.x, (_Float16)d.y, (_Float16)d.z, (_Float16)d.w};
    }
  }

  // ---- epilogue thread state: tid<64 owns (seq = tid>>4, cols ec0,ec0+1)
  const int eseq = tid >> 4;
  const int ec0  = (tid & 15) * 2;
  const int ej   = slice * 32 + ec0;
  float hr0 = 0.f, hr1 = 0.f;
  float br0 = 0, br1 = 0, bz0 = 0, bz1 = 0, bn0 = 0, bn1 = 0;
  int mylen = 0;
  if (tid < 64) {
    br0 = bhh[ej];        br1 = bhh[ej + 1];
    bz0 = bhh[ej + 512];  bz1 = bhh[ej + 513];
    bn0 = bhh[ej + 1024]; bn1 = bhh[ej + 1025];
    mylen = lens[b0 + eseq];
  }
  const int glen = max(max(lens[b0], lens[b0 + 1]), max(lens[b0 + 2], lens[b0 + 3]));
  unsigned int* fgrp = flags + grp * 16;   // one 64B line per group
  __syncthreads();

  const int arow = lane & 15;
  const int ak   = (lane >> 4) * 8;
  const _Float16* hbase = &h16[arow * 520 + ak];

  for (int t = 0; t < glen; ++t) {
    // ---- matvec: gh[seq][row] for this wave's 32 rows
    v4f acc0 = (v4f){0.f, 0.f, 0.f, 0.f};
    v4f acc1 = (v4f){0.f, 0.f, 0.f, 0.f};
#pragma unroll
    for (int kt = 0; kt < 16; ++kt) {
      v8h af = *(const v8h*)(hbase + kt * 32);
      acc0 = __builtin_amdgcn_mfma_f32_16x16x32_f16(af, bw0[kt], acc0, 0, 0, 0);
      acc1 = __builtin_amdgcn_mfma_f32_16x16x32_f16(af, bw1[kt], acc1, 0, 0, 0);
    }
    if (lane < 16) {  // lanes 0..15: reg p = seq p, col n = lane
      *(v4f*)&ghl[(w * 32 + lane) * 4]      = acc0;
      *(v4f*)&ghl[(w * 32 + 16 + lane) * 4] = acc1;
    }
    __syncthreads();

    if (tid < 64) {
      const float ar0 = ghl[(0 * 32 + ec0) * 4 + eseq], ar1 = ghl[(0 * 32 + ec0 + 1) * 4 + eseq];
      const float az0 = ghl[(1 * 32 + ec0) * 4 + eseq], az1 = ghl[(1 * 32 + ec0 + 1) * 4 + eseq];
      const float an0 = ghl[(2 * 32 + ec0) * 4 + eseq], an1 = ghl[(2 * 32 + ec0 + 1) * 4 + eseq];
      const _Float16* gxr = gx + ((size_t)t * BATCH + b0 + eseq) * G3 + ej;
      union { unsigned u; _Float16 h[2]; } g0, g1, g2, pk;
      g0.u = *(const unsigned*)gxr;
      g1.u = *(const unsigned*)(gxr + 512);
      g2.u = *(const unsigned*)(gxr + 1024);
      float* o = out + (size_t)t * (BATCH * HID) + (size_t)(b0 + eseq) * HID + ej;
      if (t < mylen) {
        const float r0 = 1.f / (1.f + __expf(-((float)g0.h[0] + ar0 + br0)));
        const float z0 = 1.f / (1.f + __expf(-((float)g1.h[0] + az0 + bz0)));
        const float p0 = (float)g2.h[0] + r0 * (an0 + bn0);
        const float n0v = 1.f - 2.f / (__expf(2.f * p0) + 1.f);
        hr0 = (1.f - z0) * n0v + z0 * hr0;
        const float r1 = 1.f / (1.f + __expf(-((float)g0.h[1] + ar1 + br1)));
        const float z1 = 1.f / (1.f + __expf(-((float)g1.h[1] + az1 + bz1)));
        const float p1 = (float)g2.h[1] + r1 * (an1 + bn1);
        const float n1v = 1.f - 2.f / (__expf(2.f * p1) + 1.f);
        hr1 = (1.f - z1) * n1v + z1 * hr1;
        o[0] = hr0; o[1] = hr1;
      } else {
        o[0] = 0.f; o[1] = 0.f;  // zero-padded past sequence end
      }
      // publish h (frozen if inactive): relaxed sc1 store, no cache ops
      pk.h[0] = (_Float16)hr0; pk.h[1] = (_Float16)hr1;
      const size_t di = (size_t)((((t + 1) & 1) * NGROUP + grp) * SPG + eseq) * 256
                        + slice * 16 + (tid & 15);
      __hip_atomic_store((unsigned*)hbuf + di, pk.u, __ATOMIC_RELAXED,
                         __HIP_MEMORY_SCOPE_AGENT);
    }
    // barrier's vmcnt(0) drain = publish stores complete at coherence point
    __syncthreads();
    if (tid == 0)
      __hip_atomic_store(fgrp + slice, (unsigned)(t + 1), __ATOMIC_RELEASE,
                         __HIP_MEMORY_SCOPE_AGENT);
    if (tid < 16) {  // poll: relaxed sc1 loads only — no buffer_inv
      while (__hip_atomic_load(fgrp + tid, __ATOMIC_RELAXED,
                               __HIP_MEMORY_SCOPE_AGENT) < (unsigned)(t + 1))
        __builtin_amdgcn_s_sleep(1);
    }
    __syncthreads();
    // ---- pull full h for next step: 4 seq x 512 f16 = 512 u64 (sc1 relaxed)
    const unsigned long long* src = (const unsigned long long*)hbuf
        + (size_t)(((t + 1) & 1) * NGROUP + grp) * SPG * 128;
    for (int i = tid; i < SPG * 128; i += 192) {
      const unsigned long long v = __hip_atomic_load(src + i, __ATOMIC_RELAXED,
                                                     __HIP_MEMORY_SCOPE_AGENT);
      const int sq = i >> 7, i2 = i & 127;
      *(unsigned long long*)&h16[sq * 520 + i2 * 4] = v;
    }
    __syncthreads();
  }

  if (tid < 64) {
    for (int t = glen; t < T_STEPS; ++t) {
      float* o = out + (size_t)t * (BATCH * HID) + (size_t)(b0 + eseq) * HID + ej;
      o[0] = 0.f; o[1] = 0.f;
    }
    float* hl = out + (size_t)T_STEPS * BATCH * HID + (size_t)(b0 + eseq) * HID + ej;
    hl[0] = hr0; hl[1] = hr1;
  }
}

// ---------------------------------------------------------------------------
extern "C" void kernel_launch(void* const* d_in, const int* in_sizes, int n_in,
                              void* d_out, int out_size, void* d_ws, size_t ws_size,
                              hipStream_t stream) {
  const float* x    = (const float*)d_in[0];
  const int*   lens = (const int*)d_in[1];
  const float* w_ih = (const float*)d_in[2];
  const float* w_hh = (const float*)d_in[3];
  const float* b_ih = (const float*)d_in[4];
  const float* b_hh = (const float*)d_in[5];
  float* out = (float*)d_out;

  // ws: gx f16 [65536][1536] = 192 MiB | hbuf f16 2x16x4x512 = 128 KiB | flags 1 KiB
  _Float16* gxbuf = (_Float16*)d_ws;
  _Float16* hbuf  = gxbuf + (size_t)M_ROWS * G3;
  unsigned int* flags = (unsigned int*)(hbuf + 2 * NGROUP * SPG * HID);

  zero_flags<<<dim3(1), dim3(NGROUP * NSLICE), 0, stream>>>(flags);
  gemm_gx<<<dim3(G3 / BN, M_ROWS / BM), dim3(256), 0, stream>>>(x, w_ih, b_ih, gxbuf);
  gru_scan2<<<dim3(NSLICE * NGROUP), dim3(192), 0, stream>>>(
      gxbuf, w_hh, lens, b_hh, out, hbuf, flags);
}

// Round 5
// 2530.721 us; speedup vs baseline: 17.4215x; 1.8384x over previous
//
#include <hip/hip_runtime.h>

// (T,B,I,H) = (1024, 64, 512, 512)
#define T_STEPS 1024
#define BATCH   64
#define IN_F    512
#define HID     512
#define G3      1536
#define M_ROWS  (T_STEPS * BATCH)

#define NSLICE  16   // weight-row slices (96 rows each, reg-resident)
#define NGROUP  16   // batch groups (4 sequences each)
#define SPG     4    // sequences per group
#define HB_U64  (2 * NGROUP * SPG * 256)   // ping-pong hbuf, u64 entries

typedef _Float16 v8h  __attribute__((ext_vector_type(8)));
typedef float    v4f  __attribute__((ext_vector_type(4)));

// ---------------------------------------------------------------------------
// gx = x * w_ih^T + b_ih -> f16 [65536][1536]   (unchanged, passing)
// ---------------------------------------------------------------------------
#define BM 64
#define BN 128
#define BK 32
#define LDP 40

__global__ __launch_bounds__(256) void gemm_gx(
    const float* __restrict__ X, const float* __restrict__ W,
    const float* __restrict__ bias, _Float16* __restrict__ C) {
  __shared__ _Float16 As[BM][LDP];
  __shared__ _Float16 Bs[BN][LDP];
  const int tid  = threadIdx.x;
  const int lane = tid & 63;
  const int wave = tid >> 6;
  const int m0 = blockIdx.y * BM;
  const int n0 = blockIdx.x * BN;

  v4f acc[8];
#pragma unroll
  for (int i = 0; i < 8; ++i) acc[i] = (v4f){0.f, 0.f, 0.f, 0.f};

  const int srow  = tid >> 2;
  const int kpart = (tid & 3) * 8;
  const int fr = lane & 15;
  const int ko = (lane >> 4) * 8;

  for (int kc = 0; kc < IN_F; kc += BK) {
    {
      const float* s = X + (size_t)(m0 + srow) * IN_F + kc + kpart;
      float4 a = *(const float4*)s;
      float4 b = *(const float4*)(s + 4);
      v8h o = {(_Float16)a.x, (_Float16)a.y, (_Float16)a.z, (_Float16)a.w,
               (_Float16)b.x, (_Float16)b.y, (_Float16)b.z, (_Float16)b.w};
      *(v8h*)&As[srow][kpart] = o;
    }
#pragma unroll
    for (int r = 0; r < 2; ++r) {
      const float* s = W + (size_t)(n0 + r * 64 + srow) * IN_F + kc + kpart;
      float4 a = *(const float4*)s;
      float4 b = *(const float4*)(s + 4);
      v8h o = {(_Float16)a.x, (_Float16)a.y, (_Float16)a.z, (_Float16)a.w,
               (_Float16)b.x, (_Float16)b.y, (_Float16)b.z, (_Float16)b.w};
      *(v8h*)&Bs[r * 64 + srow][kpart] = o;
    }
    __syncthreads();
    v8h af = *(const v8h*)&As[wave * 16 + fr][ko];
#pragma unroll
    for (int nt = 0; nt < 8; ++nt) {
      v8h bf = *(const v8h*)&Bs[nt * 16 + fr][ko];
      acc[nt] = __builtin_amdgcn_mfma_f32_16x16x32_f16(af, bf, acc[nt], 0, 0, 0);
    }
    __syncthreads();
  }

  const int rq = lane >> 4;
#pragma unroll
  for (int nt = 0; nt < 8; ++nt) {
    const int gcol = n0 + nt * 16 + fr;
    const float bv = bias[gcol];
#pragma unroll
    for (int r = 0; r < 4; ++r) {
      const int grow = m0 + wave * 16 + rq * 4 + r;
      C[(size_t)grow * G3 + gcol] = (_Float16)(acc[nt][r] + bv);
    }
  }
}

__global__ void zero_hbuf(unsigned long long* h) {
  const int i = blockIdx.x * 256 + threadIdx.x;
  if (i < HB_U64) h[i] = 0ull;
}

// ---------------------------------------------------------------------------
// Persistent-weight GRU scan, self-tagged exchange.
// 256 WGs = 16 slices x 16 groups; WG=192 (3 waves = 3 gates), weights
// reg-resident as MFMA B-frags. Cross-WG h exchange: each h-pair published
// as u64 [tag=t+1 | h1:f16 | h0:f16] via relaxed agent-scope (sc1) store into
// a ping-pong slot; readers poll the DATA tags directly (no flag, no drain,
// no release/acquire cache ops). gx for step t+1 prefetched during step t.
// Plain launch; __launch_bounds__(192,2) => 256 blocks always co-resident.
// ---------------------------------------------------------------------------
__global__ __launch_bounds__(192, 2) void gru_scan2(
    const _Float16* __restrict__ gx, const float* __restrict__ whh,
    const int* __restrict__ lens, const float* __restrict__ bhh,
    float* __restrict__ out, unsigned long long* hbuf) {
  const int bid   = blockIdx.x;
  const int slice = bid >> 4;
  const int grp   = bid & 15;
  const int b0  = grp * SPG;
  const int tid  = threadIdx.x;
  const int lane = tid & 63;
  const int w    = tid >> 6;    // wave = gate (0:r 1:z 2:n)

  __shared__ __align__(16) _Float16 h16[16 * 520];  // +8 pad
  __shared__ __align__(16) float ghl[3 * 32 * 4];   // [gate][col][seq]

  for (int i = tid; i < 16 * 520 / 2; i += 192) ((unsigned*)h16)[i] = 0u;

  // ---- persistent weight B-frags: wave w, rows = w*512 + slice*32 + [0,32)
  v8h bw0[16], bw1[16];
  {
    const int r15 = lane & 15;
    const int k8  = (lane >> 4) * 8;
    const float* p0 = whh + (size_t)(w * 512 + slice * 32 + r15) * HID + k8;
    const float* p1 = p0 + 16 * HID;
#pragma unroll
    for (int kt = 0; kt < 16; ++kt) {
      float4 a = *(const float4*)(p0 + kt * 32);
      float4 b = *(const float4*)(p0 + kt * 32 + 4);
      bw0[kt] = (v8h){(_Float16)a.x, (_Float16)a.y, (_Float16)a.z, (_Float16)a.w,
                      (_Float16)b.x, (_Float16)b.y, (_Float16)b.z, (_Float16)b.w};
      float4 c = *(const float4*)(p1 + kt * 32);
      float4 d = *(const float4*)(p1 + kt * 32 + 4);
      bw1[kt] = (v8h){(_Float16)c.x, (_Float16)c.y, (_Float16)c.z, (_Float16)c.w,
                      (_Float16)d.x, (_Float16)d.y, (_Float16)d.z, (_Float16)d.w};
    }
  }

  // ---- epilogue thread state: tid<64 owns (seq = tid>>4, cols ec0,ec0+1)
  const int eseq = tid >> 4;
  const int ec0  = (tid & 15) * 2;
  const int ej   = slice * 32 + ec0;
  float hr0 = 0.f, hr1 = 0.f;
  float br0 = 0, br1 = 0, bz0 = 0, bz1 = 0, bn0 = 0, bn1 = 0;
  int mylen = 0;
  unsigned pg0 = 0, pg1 = 0, pg2 = 0;   // prefetched gx (2 f16 each gate)
  if (tid < 64) {
    br0 = bhh[ej];        br1 = bhh[ej + 1];
    bz0 = bhh[ej + 512];  bz1 = bhh[ej + 513];
    bn0 = bhh[ej + 1024]; bn1 = bhh[ej + 1025];
    mylen = lens[b0 + eseq];
    const _Float16* gxr = gx + ((size_t)0 * BATCH + b0 + eseq) * G3 + ej;
    pg0 = *(const unsigned*)gxr;
    pg1 = *(const unsigned*)(gxr + 512);
    pg2 = *(const unsigned*)(gxr + 1024);
  }
  const int glen = max(max(lens[b0], lens[b0 + 1]), max(lens[b0 + 2], lens[b0 + 3]));
  __syncthreads();

  const int arow = lane & 15;
  const int ak   = (lane >> 4) * 8;
  const _Float16* hbase = &h16[arow * 520 + ak];

  // pull-set indices for this thread (<=6 of the group's 1024 u64s)
  int ii[6]; int nn = 0;
  for (int i = tid; i < SPG * 256; i += 192) { ii[nn] = i; ++nn; }

  for (int t = 0; t < glen; ++t) {
    // ---- matvec: gh[seq][row] for this wave's 32 rows
    v4f acc0 = (v4f){0.f, 0.f, 0.f, 0.f};
    v4f acc1 = (v4f){0.f, 0.f, 0.f, 0.f};
#pragma unroll
    for (int kt = 0; kt < 16; ++kt) {
      v8h af = *(const v8h*)(hbase + kt * 32);
      acc0 = __builtin_amdgcn_mfma_f32_16x16x32_f16(af, bw0[kt], acc0, 0, 0, 0);
      acc1 = __builtin_amdgcn_mfma_f32_16x16x32_f16(af, bw1[kt], acc1, 0, 0, 0);
    }
    if (lane < 16) {  // lanes 0..15: reg p = seq p, col n = lane
      *(v4f*)&ghl[(w * 32 + lane) * 4]      = acc0;
      *(v4f*)&ghl[(w * 32 + 16 + lane) * 4] = acc1;
    }
    __syncthreads();   // ghl ready; all h16 MFMA reads done

    if (tid < 64) {
      const float ar0 = ghl[(0 * 32 + ec0) * 4 + eseq], ar1 = ghl[(0 * 32 + ec0 + 1) * 4 + eseq];
      const float az0 = ghl[(1 * 32 + ec0) * 4 + eseq], az1 = ghl[(1 * 32 + ec0 + 1) * 4 + eseq];
      const float an0 = ghl[(2 * 32 + ec0) * 4 + eseq], an1 = ghl[(2 * 32 + ec0 + 1) * 4 + eseq];
      union { unsigned u; _Float16 h[2]; } g0, g1, g2, pk;
      g0.u = pg0; g1.u = pg1; g2.u = pg2;
      float* o = out + (size_t)t * (BATCH * HID) + (size_t)(b0 + eseq) * HID + ej;
      if (t < mylen) {
        const float r0 = 1.f / (1.f + __expf(-((float)g0.h[0] + ar0 + br0)));
        const float z0 = 1.f / (1.f + __expf(-((float)g1.h[0] + az0 + bz0)));
        const float p0 = (float)g2.h[0] + r0 * (an0 + bn0);
        const float n0v = 1.f - 2.f / (__expf(2.f * p0) + 1.f);
        hr0 = (1.f - z0) * n0v + z0 * hr0;
        const float r1 = 1.f / (1.f + __expf(-((float)g0.h[1] + ar1 + br1)));
        const float z1 = 1.f / (1.f + __expf(-((float)g1.h[1] + az1 + bz1)));
        const float p1 = (float)g2.h[1] + r1 * (an1 + bn1);
        const float n1v = 1.f - 2.f / (__expf(2.f * p1) + 1.f);
        hr1 = (1.f - z1) * n1v + z1 * hr1;
        o[0] = hr0; o[1] = hr1;
      } else {
        o[0] = 0.f; o[1] = 0.f;  // zero-padded past sequence end
      }
      // publish [tag | h1 | h0] (frozen h if inactive): relaxed sc1 u64 store
      pk.h[0] = (_Float16)hr0; pk.h[1] = (_Float16)hr1;
      const unsigned long long pv =
          ((unsigned long long)(unsigned)(t + 1) << 32) | pk.u;
      const size_t di = (size_t)((((t + 1) & 1) * NGROUP + grp) * SPG + eseq) * 256
                        + slice * 16 + (tid & 15);
      __hip_atomic_store(hbuf + di, pv, __ATOMIC_RELAXED,
                         __HIP_MEMORY_SCOPE_AGENT);
      // prefetch gx for next step (off critical path; clamp in-bounds)
      const int tn = (t + 1 < glen) ? t + 1 : t;
      const _Float16* gxr = gx + ((size_t)tn * BATCH + b0 + eseq) * G3 + ej;
      pg0 = *(const unsigned*)gxr;
      pg1 = *(const unsigned*)(gxr + 512);
      pg2 = *(const unsigned*)(gxr + 1024);
    }

    // ---- tagged pull: poll data u64s until tag >= t+1, land into h16
    {
      const unsigned long long* src = hbuf
          + (size_t)(((t + 1) & 1) * NGROUP + grp) * (SPG * 256);
      const unsigned want = (unsigned)(t + 1);
      unsigned long long got[6];
      unsigned pend = (1u << nn) - 1u;
      while (pend) {
#pragma unroll
        for (int j = 0; j < 6; ++j)
          if (j < nn && (pend & (1u << j)))
            got[j] = __hip_atomic_load(src + ii[j], __ATOMIC_RELAXED,
                                       __HIP_MEMORY_SCOPE_AGENT);
#pragma unroll
        for (int j = 0; j < 6; ++j)
          if (j < nn && (pend & (1u << j)) &&
              (unsigned)(got[j] >> 32) >= want) {
            const int sq = ii[j] >> 8, jj = ii[j] & 255;
            *(unsigned*)&h16[sq * 520 + jj * 2] = (unsigned)got[j];
            pend &= ~(1u << j);
          }
        if (pend) __builtin_amdgcn_s_sleep(1);
      }
    }
    __syncthreads();   // h16 (t+1) ready for next matvec
  }

  if (tid < 64) {
    for (int t = glen; t < T_STEPS; ++t) {
      float* o = out + (size_t)t * (BATCH * HID) + (size_t)(b0 + eseq) * HID + ej;
      o[0] = 0.f; o[1] = 0.f;
    }
    float* hl = out + (size_t)T_STEPS * BATCH * HID + (size_t)(b0 + eseq) * HID + ej;
    hl[0] = hr0; hl[1] = hr1;
  }
}

// ---------------------------------------------------------------------------
extern "C" void kernel_launch(void* const* d_in, const int* in_sizes, int n_in,
                              void* d_out, int out_size, void* d_ws, size_t ws_size,
                              hipStream_t stream) {
  const float* x    = (const float*)d_in[0];
  const int*   lens = (const int*)d_in[1];
  const float* w_ih = (const float*)d_in[2];
  const float* w_hh = (const float*)d_in[3];
  const float* b_ih = (const float*)d_in[4];
  const float* b_hh = (const float*)d_in[5];
  float* out = (float*)d_out;

  // ws: gx f16 [65536][1536] = 192 MiB | hbuf u64[32768] = 256 KiB
  _Float16* gxbuf = (_Float16*)d_ws;
  unsigned long long* hbuf = (unsigned long long*)(gxbuf + (size_t)M_ROWS * G3);

  zero_hbuf<<<dim3((HB_U64 + 255) / 256), dim3(256), 0, stream>>>(hbuf);
  gemm_gx<<<dim3(G3 / BN, M_ROWS / BM), dim3(256), 0, stream>>>(x, w_ih, b_ih, gxbuf);
  gru_scan2<<<dim3(NSLICE * NGROUP), dim3(192), 0, stream>>>(
      gxbuf, w_hh, lens, b_hh, out, hbuf);
}